// Round 2
// baseline (55.879 us; speedup 1.0000x reference)
//
#include <hip/hip_runtime.h>
#include <hip/hip_bf16.h>

// Shapes (fixed): D=1, S=64, A=128, P=K=6, T=80
#define NS 64
#define NA 128
#define NK 6
#define NT 80
#define THREADS 256

// transpose tiling: 8 agents (48 rows) x 16 timesteps
#define TILE_A 8
#define TILE_T 16
#define NROWS (TILE_A * NK)          // 48
#define N_TT (NT / TILE_T)           // 5
#define NBT (NS * (NA / TILE_A) * N_TT)  // 64*16*5 = 5120 transpose blocks
#define NBS (NS * (NA / TILE_A))         // 64*16 = 1024 score blocks (8 agents each)

// Output layout (flat concat, float):
//   waymo_valid  [S,T,A]        655360
//   waymo_trajs  [S,T,A,K,2]    7864320
//   waymo_scores [S,A,K]        49152
//   waymo_yaw    [S,T,A,K,1]    3932160
#define OFF_TRAJ   655360
#define OFF_SCORE  (655360 + 7864320)
#define OFF_YAW    (655360 + 7864320 + 49152)

typedef float nfloat2 __attribute__((ext_vector_type(2)));

__global__ __launch_bounds__(THREADS) void waymo_post_kernel(
    const int*    __restrict__ validIn,  // [S,A] (bool -> int32)
    const float*  __restrict__ confIn,   // [1,S,A,K]
    const float2* __restrict__ posIn,    // [1,S,A,K,T] as float2
    const float*  __restrict__ yawIn,    // [1,S,A,K,T]
    const float*  __restrict__ typeIn,   // [S,A,3] one-hot
    float*        __restrict__ out)
{
    const int g   = blockIdx.x;
    const int tid = threadIdx.x;

    float*  outV  = out;                        // [S,T,A]
    float2* outT  = (float2*)(out + OFF_TRAJ);  // [S,T,A,K] float2
    float*  outSc = out + OFF_SCORE;            // [S,A,K]
    float*  outY  = out + OFF_YAW;              // [S,T,A,K]

    __shared__ float2 sPos[NROWS * 17];  // row stride 17 float2
    __shared__ float  sYaw[NROWS * 17];

    if ((g % 6) != 0) {
        // ======================= TRANSPOSE ROLE =======================
        const int tb  = g - (g / 6 + 1);     // 0..5119
        const int s   = tb / ((NA / TILE_A) * N_TT);
        const int rem = tb % ((NA / TILE_A) * N_TT);
        const int at  = rem / N_TT;
        const int tt  = rem % N_TT;
        const int a0  = at * TILE_A;
        const int t0  = tt * TILE_T;

        const size_t base = ((size_t)(s * NA + a0)) * NK * NT;  // element units

        // stage: 48 rows x 16 t, coalesced 128B (pos) / 64B (yaw) per row-chunk
        for (int i = tid; i < NROWS * TILE_T; i += THREADS) {
            int r = i >> 4;           // 0..47
            int t = i & (TILE_T - 1); // 0..15
            sPos[r * 17 + t] = posIn[base + (size_t)r * NT + t0 + t];
            sYaw[r * 17 + t] = yawIn[base + (size_t)r * NT + t0 + t];
        }
        __syncthreads();

        // write: for each t, 48 consecutive (a,k) -> 384B/192B runs
        for (int o = tid; o < NROWS * TILE_T; o += THREADS) {
            int t = o / NROWS;        // 0..15
            int r = o - t * NROWS;    // 0..47 == la*6+k
            int la = r / NK;
            int k  = r - la * NK;
            size_t oidx = ((size_t)(s * NT + t0 + t) * NA + (a0 + la)) * NK + k;
            float2 pv = sPos[r * 17 + t];
            __builtin_nontemporal_store(*(nfloat2*)&pv, (nfloat2*)&outT[oidx]);
            __builtin_nontemporal_store(sYaw[r * 17 + t], &outY[oidx]);
        }

        // valid broadcast for this (s, t-tile, a-tile)
        for (int o = tid; o < TILE_T * TILE_A; o += THREADS) {
            int t  = o >> 3;
            int la = o & 7;
            float v = (validIn[(size_t)s * NA + a0 + la] != 0) ? 1.0f : 0.0f;
            __builtin_nontemporal_store(v, &outV[(size_t)(s * NT + t0 + t) * NA + a0 + la]);
        }
    } else {
        // ========================= SCORE ROLE =========================
        const int sb = g / 6;                 // 0..1023
        const int s  = sb / (NA / TILE_A);
        const int a0 = (sb % (NA / TILE_A)) * TILE_A;

        const int la   = tid >> 5;    // agent within tile
        const int lane = tid & 31;
        const int a    = a0 + la;
        const int p    = lane >> 1;   // pair slot 0..15 (15 used)
        const int half = lane & 1;    // time half

        const size_t sa = (size_t)s * NA + a;
        const float th = 2.5f * typeIn[sa * 3 + 0]
                       + 1.0f * typeIn[sa * 3 + 1]
                       + 1.5f * typeIn[sa * 3 + 2];

        // pair slot -> (i,j), i<j, row-major upper triangle of 6x6
        int pi, pj;
        if      (p < 5)  { pi = 0; pj = p + 1; }
        else if (p < 9)  { pi = 1; pj = p - 3; }
        else if (p < 12) { pi = 2; pj = p - 6; }
        else if (p < 14) { pi = 3; pj = p - 8; }
        else             { pi = 4; pj = 5;     }

        const float2* row = posIn + sa * (NK * NT);
        float dsum = 0.f;
        #pragma unroll 8
        for (int t = half * 40; t < half * 40 + 40; ++t) {
            float2 u = row[pi * NT + t];
            float2 v = row[pj * NT + t];
            float dx = u.x - v.x, dy = u.y - v.y;
            dsum += sqrtf(dx * dx + dy * dy);
        }
        dsum += __shfl_xor(dsum, 1);
        const bool within = (dsum / 80.0f) < th;
        const bool predb  = (half == 0) && (p < 15) && within;
        unsigned long long bal = __ballot(predb);
        unsigned mask32 = (unsigned)(bal >> (tid & 32));  // this agent's 32 bits

        if (lane == 0) {
            // softmax over K=6 (stable) + renorm
            float c[NK];
            float mx = -3e38f;
            for (int q = 0; q < NK; ++q) { c[q] = confIn[sa * NK + q]; mx = fmaxf(mx, c[q]); }
            float ssum = 0.f;
            for (int q = 0; q < NK; ++q) { c[q] = expf(c[q] - mx); ssum += c[q]; }
            for (int q = 0; q < NK; ++q) c[q] /= ssum;
            ssum = 0.f;
            for (int q = 0; q < NK; ++q) ssum += c[q];
            for (int q = 0; q < NK; ++q) c[q] /= ssum;

            // stable descending argsort (selection; strict > keeps earliest on ties)
            int ord[NK]; bool used[NK];
            for (int q = 0; q < NK; ++q) used[q] = false;
            for (int st = 0; st < NK; ++st) {
                int best = 0; float bv = -3e38f;
                for (int q = 0; q < NK; ++q)
                    if (!used[q] && c[q] > bv) { bv = c[q]; best = q; }
                used[best] = true; ord[st] = best;
            }

            float cur[NK];
            for (int q = 0; q < NK; ++q) cur[q] = c[q];

            if (validIn[sa] != 0) {
                for (int st = 0; st < NK; ++st) {
                    int k = ord[st];
                    float ck = cur[k];
                    bool any = false;
                    for (int j = 0; j < NK; ++j) {
                        if (j == k) continue;
                        int lo = j < k ? j : k;
                        int hi = j < k ? k : j;
                        int pidx = lo * 5 - (lo * (lo - 1)) / 2 + (hi - lo - 1);
                        if (((mask32 >> (2 * pidx)) & 1u) && (cur[j] > ck)) any = true;
                    }
                    if (any) cur[k] = 0.001f;
                }
            }

            // renormalize, then softmax(log(s)/0.5) == s^2 / sum(s^2)
            float tsum = 0.f;
            for (int q = 0; q < NK; ++q) tsum += cur[q];
            float w[NK]; float wsum = 0.f;
            for (int q = 0; q < NK; ++q) {
                float qq = cur[q] / tsum;
                w[q] = qq * qq; wsum += w[q];
            }
            for (int q = 0; q < NK; ++q) outSc[sa * NK + q] = w[q] / wsum;
        }
    }
}

extern "C" void kernel_launch(void* const* d_in, const int* in_sizes, int n_in,
                              void* d_out, int out_size, void* d_ws, size_t ws_size,
                              hipStream_t stream) {
    const int*    validIn = (const int*)d_in[0];
    const float*  confIn  = (const float*)d_in[1];
    const float2* posIn   = (const float2*)d_in[2];
    const float*  yawIn   = (const float*)d_in[3];
    const float*  typeIn  = (const float*)d_in[4];
    float* out = (float*)d_out;

    waymo_post_kernel<<<NBT + NBS, THREADS, 0, stream>>>(validIn, confIn, posIn, yawIn, typeIn, out);
}

// Round 3
// 46.426 us; speedup vs baseline: 1.2036x; 1.2036x over previous
//
#include <hip/hip_runtime.h>
#include <hip/hip_bf16.h>

// Shapes (fixed): D=1, S=64, A=128, P=K=6, T=80
#define NS 64
#define NA 128
#define NK 6
#define NT 80

// Output layout (flat concat, float):
//   waymo_valid  [S,T,A]        655360
//   waymo_trajs  [S,T,A,K,2]    7864320
//   waymo_scores [S,A,K]        49152
//   waymo_yaw    [S,T,A,K,1]    3932160
#define OFF_TRAJ   655360
#define OFF_SCORE  (655360 + 7864320)
#define OFF_YAW    (655360 + 7864320 + 49152)

typedef float nfloat4 __attribute__((ext_vector_type(4)));

// ---------------- transpose kernel: trajs + yaw + valid ----------------
// tile: 16 agents (96 rows) x 16 timesteps; 64*8*5 = 2560 blocks
#define TA 16
#define TT 16
#define RT (TA * NK)   // 96

__global__ __launch_bounds__(256) void waymo_transpose_kernel(
    const int*    __restrict__ validIn,  // [S,A]
    const float2* __restrict__ posIn,    // [S,A,K,T] float2
    const float*  __restrict__ yawIn,    // [S,A,K,T]
    float*        __restrict__ out)
{
    const int g   = blockIdx.x;          // 0..2559
    const int tid = threadIdx.x;
    const int s   = g / 40;              // 8 a-tiles * 5 t-chunks
    const int rem = g - s * 40;
    const int a0  = (rem / 5) * TA;
    const int t0  = (rem - (rem / 5) * 5) * TT;

    __shared__ float2 sT[TT][RT + 1];    // transposed: [t][row], stride 97 float2
    __shared__ float  yT[TT][RT + 1];

    const size_t sa0 = (size_t)s * NA + a0;
    const float2* pbase = posIn + sa0 * (NK * NT);
    const float*  ybase = yawIn + sa0 * (NK * NT);

    // stage pos: 768 float4 loads (3/thread), each = 2 timesteps of one row
    for (int i = tid; i < RT * 8; i += 256) {
        int r = i >> 3, l = i & 7;                  // row, float4-slot
        nfloat4 v = *(const nfloat4*)(pbase + (size_t)r * NT + t0 + 2 * l);
        sT[2 * l + 0][r] = float2{v.x, v.y};
        sT[2 * l + 1][r] = float2{v.z, v.w};
    }
    // stage yaw: 384 float4 loads (1.5/thread), each = 4 timesteps of one row
    for (int i = tid; i < RT * 4; i += 256) {
        int r = i >> 2, m = i & 3;
        nfloat4 v = *(const nfloat4*)(ybase + (size_t)r * NT + t0 + 4 * m);
        yT[4 * m + 0][r] = v.x;
        yT[4 * m + 1][r] = v.y;
        yT[4 * m + 2][r] = v.z;
        yT[4 * m + 3][r] = v.w;
    }
    __syncthreads();

    // trajs out: per t, 96 float2 = 48 float4 contiguous (768B runs)
    nfloat4* trajOut = (nfloat4*)(out + OFF_TRAJ);
    for (int o = tid; o < TT * 48; o += 256) {
        int t = o / 48, j = o - (o / 48) * 48;
        size_t f4 = (((size_t)(s * NT + t0 + t) * NA + a0) * NK) >> 1;
        float2 u = sT[t][2 * j], w = sT[t][2 * j + 1];
        nfloat4 v{u.x, u.y, w.x, w.y};
        __builtin_nontemporal_store(v, trajOut + f4 + j);
    }
    // yaw out: per t, 96 floats = 24 float4 (384B runs)
    nfloat4* yawOut = (nfloat4*)(out + OFF_YAW);
    for (int o = tid; o < TT * 24; o += 256) {
        int t = o / 24, j = o - (o / 24) * 24;
        size_t f4 = (((size_t)(s * NT + t0 + t) * NA + a0) * NK) >> 2;
        nfloat4 v{yT[t][4 * j], yT[t][4 * j + 1], yT[t][4 * j + 2], yT[t][4 * j + 3]};
        __builtin_nontemporal_store(v, yawOut + f4 + j);
    }
    // valid out: 16t x 16a = 64 float4, one wave
    if (tid < 64) {
        int t = tid >> 2, q = tid & 3;
        nfloat4 v;
        v.x = (validIn[sa0 + 4 * q + 0] != 0) ? 1.0f : 0.0f;
        v.y = (validIn[sa0 + 4 * q + 1] != 0) ? 1.0f : 0.0f;
        v.z = (validIn[sa0 + 4 * q + 2] != 0) ? 1.0f : 0.0f;
        v.w = (validIn[sa0 + 4 * q + 3] != 0) ? 1.0f : 0.0f;
        size_t f4 = ((size_t)(s * NT + t0 + t) * NA + a0) >> 2;
        __builtin_nontemporal_store(v, (nfloat4*)out + f4 + q);
    }
}

// ---------------- score kernel: softmax + NMS (round-1 verified logic) ----------------
// 8 agents per block, 1024 blocks; pos staged to LDS with float4
#define SA8 8

__global__ __launch_bounds__(256) void waymo_score_kernel(
    const int*    __restrict__ validIn,
    const float*  __restrict__ confIn,
    const float2* __restrict__ posIn,
    const float*  __restrict__ typeIn,
    float*        __restrict__ out)
{
    const int g   = blockIdx.x;          // 0..1023
    const int tid = threadIdx.x;
    const int s   = g / (NA / SA8);
    const int a0  = (g - s * (NA / SA8)) * SA8;

    __shared__ float2 sPos[SA8 * NK * 82];   // stride 82 float2 (656B, 16B-aligned rows)

    const size_t sab = (size_t)s * NA + a0;
    const float2* pbase = posIn + sab * (NK * NT);

    // stage: 48 rows x 80 t = 1920 float4 (7.5/thread), coalesced 640B per row
    for (int i = tid; i < SA8 * NK * (NT / 2); i += 256) {
        int r = i / 40, q = i - (i / 40) * 40;
        nfloat4 v = *(const nfloat4*)(pbase + (size_t)r * NT + 2 * q);
        *(nfloat4*)&sPos[r * 82 + 2 * q] = v;
    }
    __syncthreads();

    float* outSc = out + OFF_SCORE;

    const int la   = tid >> 5;    // agent within tile
    const int lane = tid & 31;
    const int a    = a0 + la;
    const int p    = lane >> 1;   // pair slot 0..15 (15 used)
    const int half = lane & 1;    // time half

    const size_t sa = (size_t)s * NA + a;
    const float th = 2.5f * typeIn[sa * 3 + 0]
                   + 1.0f * typeIn[sa * 3 + 1]
                   + 1.5f * typeIn[sa * 3 + 2];

    int pi, pj;
    if      (p < 5)  { pi = 0; pj = p + 1; }
    else if (p < 9)  { pi = 1; pj = p - 3; }
    else if (p < 12) { pi = 2; pj = p - 6; }
    else if (p < 14) { pi = 3; pj = p - 8; }
    else             { pi = 4; pj = 5;     }

    const int rI = la * NK + pi, rJ = la * NK + pj;
    float dsum = 0.f;
    for (int t = half * 40; t < half * 40 + 40; ++t) {
        float2 u = sPos[rI * 82 + t];
        float2 v = sPos[rJ * 82 + t];
        float dx = u.x - v.x, dy = u.y - v.y;
        dsum += sqrtf(dx * dx + dy * dy);
    }
    dsum += __shfl_xor(dsum, 1);
    const bool within = (dsum / 80.0f) < th;
    const bool predb  = (half == 0) && (p < 15) && within;
    unsigned long long bal = __ballot(predb);
    unsigned mask32 = (unsigned)(bal >> (tid & 32));  // this agent's 32 bits

    if (lane == 0) {
        // softmax over K=6 (stable) + renorm
        float c[NK];
        float mx = -3e38f;
        for (int q = 0; q < NK; ++q) { c[q] = confIn[sa * NK + q]; mx = fmaxf(mx, c[q]); }
        float ssum = 0.f;
        for (int q = 0; q < NK; ++q) { c[q] = expf(c[q] - mx); ssum += c[q]; }
        for (int q = 0; q < NK; ++q) c[q] /= ssum;
        ssum = 0.f;
        for (int q = 0; q < NK; ++q) ssum += c[q];
        for (int q = 0; q < NK; ++q) c[q] /= ssum;

        // stable descending argsort (selection; strict > keeps earliest on ties)
        int ord[NK]; bool used[NK];
        for (int q = 0; q < NK; ++q) used[q] = false;
        for (int st = 0; st < NK; ++st) {
            int best = 0; float bv = -3e38f;
            for (int q = 0; q < NK; ++q)
                if (!used[q] && c[q] > bv) { bv = c[q]; best = q; }
            used[best] = true; ord[st] = best;
        }

        float cur[NK];
        for (int q = 0; q < NK; ++q) cur[q] = c[q];

        if (validIn[sa] != 0) {
            for (int st = 0; st < NK; ++st) {
                int k = ord[st];
                float ck = cur[k];
                bool any = false;
                for (int j = 0; j < NK; ++j) {
                    if (j == k) continue;
                    int lo = j < k ? j : k;
                    int hi = j < k ? k : j;
                    int pidx = lo * 5 - (lo * (lo - 1)) / 2 + (hi - lo - 1);
                    if (((mask32 >> (2 * pidx)) & 1u) && (cur[j] > ck)) any = true;
                }
                if (any) cur[k] = 0.001f;
            }
        }

        // renormalize, then softmax(log(s)/0.5) == s^2 / sum(s^2)
        float tsum = 0.f;
        for (int q = 0; q < NK; ++q) tsum += cur[q];
        float w[NK]; float wsum = 0.f;
        for (int q = 0; q < NK; ++q) {
            float qq = cur[q] / tsum;
            w[q] = qq * qq; wsum += w[q];
        }
        for (int q = 0; q < NK; ++q) outSc[sa * NK + q] = w[q] / wsum;
    }
}

extern "C" void kernel_launch(void* const* d_in, const int* in_sizes, int n_in,
                              void* d_out, int out_size, void* d_ws, size_t ws_size,
                              hipStream_t stream) {
    const int*    validIn = (const int*)d_in[0];
    const float*  confIn  = (const float*)d_in[1];
    const float2* posIn   = (const float2*)d_in[2];
    const float*  yawIn   = (const float*)d_in[3];
    const float*  typeIn  = (const float*)d_in[4];
    float* out = (float*)d_out;

    waymo_transpose_kernel<<<NS * 8 * 5, 256, 0, stream>>>(validIn, posIn, yawIn, out);
    waymo_score_kernel<<<NS * (NA / SA8), 256, 0, stream>>>(validIn, confIn, posIn, typeIn, out);
}

// Round 5
// 36.637 us; speedup vs baseline: 1.5252x; 1.2672x over previous
//
#include <hip/hip_runtime.h>
#include <hip/hip_bf16.h>

// Shapes (fixed): D=1, S=64, A=128, P=K=6, T=80
#define NS 64
#define NA 128
#define NK 6
#define NT 80
#define THREADS 512
#define TILE_A 8
#define NROWS (TILE_A * NK)   // 48

// Output layout (flat concat, float):
//   waymo_valid  [S,T,A]        655360
//   waymo_trajs  [S,T,A,K,2]    7864320
//   waymo_scores [S,A,K]        49152
//   waymo_yaw    [S,T,A,K,1]    3932160
#define OFF_TRAJ   655360
#define OFF_SCORE  (655360 + 7864320)
#define OFF_YAW    (655360 + 7864320 + 49152)

#define PSTRIDE 82   // float2 row stride for pos (16B-aligned rows)
#define YSTRIDE 84   // float  row stride for yaw (16B-aligned rows)

typedef float nfloat4 __attribute__((ext_vector_type(4)));

__global__ __launch_bounds__(THREADS) void waymo_post_kernel(
    const int*    __restrict__ validIn,  // [S,A] (bool -> int32)
    const float*  __restrict__ confIn,   // [1,S,A,K]
    const float2* __restrict__ posIn,    // [1,S,A,K,T] float2
    const float*  __restrict__ yawIn,    // [1,S,A,K,T]
    const float*  __restrict__ typeIn,   // [S,A,3] one-hot
    float*        __restrict__ out)
{
    const int g   = blockIdx.x;          // 0..1023
    const int tid = threadIdx.x;
    const int s   = g >> 4;
    const int a0  = (g & 15) * TILE_A;

    __shared__ float2 sPos[NROWS * PSTRIDE];  // [row][t], 31.5 KB
    __shared__ float  sYaw[NROWS * YSTRIDE];  // [row][t], 15.75 KB

    const size_t sa0 = (size_t)s * NA + a0;
    const float2* pbase = posIn + sa0 * (NK * NT);
    const float*  ybase = yawIn + sa0 * (NK * NT);

    // ---- stage pos: 1920 float4, fully contiguous 30 KB range ----
    for (int i = tid; i < NROWS * (NT / 2); i += THREADS) {  // 40 float4/row
        int r = i / 40, q = i - r * 40;
        nfloat4 v = *(const nfloat4*)(pbase + (size_t)r * NT + 2 * q);
        *(nfloat4*)&sPos[r * PSTRIDE + 2 * q] = v;
    }
    // ---- stage yaw: 960 float4, contiguous 15 KB range ----
    for (int i = tid; i < NROWS * (NT / 4); i += THREADS) {  // 20 float4/row
        int r = i / 20, m = i - r * 20;
        nfloat4 v = *(const nfloat4*)(ybase + (size_t)r * NT + 4 * m);
        *(nfloat4*)&sYaw[r * YSTRIDE + 4 * m] = v;
    }
    __syncthreads();

    float* outSc = out + OFF_SCORE;

    // ---- score + NMS: waves 0..3 (32 lanes/agent); waves 4..7 skip ahead ----
    if (tid < 256) {
        const int la   = tid >> 5;
        const int lane = tid & 31;
        const int a    = a0 + la;
        const int p    = lane >> 1;   // pair slot 0..15 (15 used)
        const int half = lane & 1;    // time half

        const size_t sa = (size_t)s * NA + a;
        const float th = 2.5f * typeIn[sa * 3 + 0]
                       + 1.0f * typeIn[sa * 3 + 1]
                       + 1.5f * typeIn[sa * 3 + 2];

        int pi, pj;
        if      (p < 5)  { pi = 0; pj = p + 1; }
        else if (p < 9)  { pi = 1; pj = p - 3; }
        else if (p < 12) { pi = 2; pj = p - 6; }
        else if (p < 14) { pi = 3; pj = p - 8; }
        else             { pi = 4; pj = 5;     }

        const int rI = la * NK + pi, rJ = la * NK + pj;
        float dsum = 0.f;
        for (int t = half * 40; t < half * 40 + 40; ++t) {
            float2 u = sPos[rI * PSTRIDE + t];
            float2 v = sPos[rJ * PSTRIDE + t];
            float dx = u.x - v.x, dy = u.y - v.y;
            dsum += sqrtf(dx * dx + dy * dy);
        }
        dsum += __shfl_xor(dsum, 1);
        const bool within = (dsum / 80.0f) < th;
        const bool predb  = (half == 0) && (p < 15) && within;
        unsigned long long bal = __ballot(predb);
        unsigned mask32 = (unsigned)(bal >> (tid & 32));  // this agent's 32 bits

        if (lane == 0) {
            // softmax over K=6 (stable) + renorm
            float c[NK];
            float mx = -3e38f;
            for (int q = 0; q < NK; ++q) { c[q] = confIn[sa * NK + q]; mx = fmaxf(mx, c[q]); }
            float ssum = 0.f;
            for (int q = 0; q < NK; ++q) { c[q] = expf(c[q] - mx); ssum += c[q]; }
            for (int q = 0; q < NK; ++q) c[q] /= ssum;
            ssum = 0.f;
            for (int q = 0; q < NK; ++q) ssum += c[q];
            for (int q = 0; q < NK; ++q) c[q] /= ssum;

            // stable descending argsort (selection; strict > keeps earliest on ties)
            int ord[NK]; bool used[NK];
            for (int q = 0; q < NK; ++q) used[q] = false;
            for (int st = 0; st < NK; ++st) {
                int best = 0; float bv = -3e38f;
                for (int q = 0; q < NK; ++q)
                    if (!used[q] && c[q] > bv) { bv = c[q]; best = q; }
                used[best] = true; ord[st] = best;
            }

            float cur[NK];
            for (int q = 0; q < NK; ++q) cur[q] = c[q];

            if (validIn[sa] != 0) {
                for (int st = 0; st < NK; ++st) {
                    int k = ord[st];
                    float ck = cur[k];
                    bool any = false;
                    for (int j = 0; j < NK; ++j) {
                        if (j == k) continue;
                        int lo = j < k ? j : k;
                        int hi = j < k ? k : j;
                        int pidx = lo * 5 - (lo * (lo - 1)) / 2 + (hi - lo - 1);
                        if (((mask32 >> (2 * pidx)) & 1u) && (cur[j] > ck)) any = true;
                    }
                    if (any) cur[k] = 0.001f;
                }
            }

            // renormalize, then softmax(log(s)/0.5) == s^2 / sum(s^2)
            float tsum = 0.f;
            for (int q = 0; q < NK; ++q) tsum += cur[q];
            float w[NK]; float wsum = 0.f;
            for (int q = 0; q < NK; ++q) {
                float qq = cur[q] / tsum;
                w[q] = qq * qq; wsum += w[q];
            }
            for (int q = 0; q < NK; ++q) outSc[sa * NK + q] = w[q] / wsum;
        }
    }

    // ---- traj out: per t, 48 rows (float2) -> 24 float4 (384B runs), 1920 float4 ----
    nfloat4* trajOut = (nfloat4*)(out + OFF_TRAJ);
    for (int o = tid; o < NT * 24; o += THREADS) {
        int t = o / 24, j = o - (o / 24) * 24;
        float2 u = sPos[(2 * j + 0) * PSTRIDE + t];
        float2 w = sPos[(2 * j + 1) * PSTRIDE + t];
        nfloat4 v{u.x, u.y, w.x, w.y};
        size_t f4 = (((size_t)(s * NT + t) * NA + a0) * NK) >> 1;
        __builtin_nontemporal_store(v, trajOut + f4 + j);
    }
    // ---- yaw out: per t, 48 rows (float) -> 12 float4 (192B runs), 960 float4 ----
    nfloat4* yawOut = (nfloat4*)(out + OFF_YAW);
    for (int o = tid; o < NT * 12; o += THREADS) {
        int t = o / 12, j = o - (o / 12) * 12;
        nfloat4 v{sYaw[(4 * j + 0) * YSTRIDE + t],
                  sYaw[(4 * j + 1) * YSTRIDE + t],
                  sYaw[(4 * j + 2) * YSTRIDE + t],
                  sYaw[(4 * j + 3) * YSTRIDE + t]};
        size_t f4 = (((size_t)(s * NT + t) * NA + a0) * NK) >> 2;
        __builtin_nontemporal_store(v, yawOut + f4 + j);
    }
    // ---- valid out: per t, 8 agents -> 2 float4, 160 float4 ----
    if (tid < 160) {
        int t = tid >> 1, q = tid & 1;
        nfloat4 v;
        v.x = (validIn[sa0 + 4 * q + 0] != 0) ? 1.0f : 0.0f;
        v.y = (validIn[sa0 + 4 * q + 1] != 0) ? 1.0f : 0.0f;
        v.z = (validIn[sa0 + 4 * q + 2] != 0) ? 1.0f : 0.0f;
        v.w = (validIn[sa0 + 4 * q + 3] != 0) ? 1.0f : 0.0f;
        size_t f4 = ((size_t)(s * NT + t) * NA + a0) >> 2;
        __builtin_nontemporal_store(v, (nfloat4*)out + f4 + q);
    }
}

extern "C" void kernel_launch(void* const* d_in, const int* in_sizes, int n_in,
                              void* d_out, int out_size, void* d_ws, size_t ws_size,
                              hipStream_t stream) {
    const int*    validIn = (const int*)d_in[0];
    const float*  confIn  = (const float*)d_in[1];
    const float2* posIn   = (const float2*)d_in[2];
    const float*  yawIn   = (const float*)d_in[3];
    const float*  typeIn  = (const float*)d_in[4];
    float* out = (float*)d_out;

    waymo_post_kernel<<<NS * (NA / TILE_A), THREADS, 0, stream>>>(
        validIn, confIn, posIn, yawIn, typeIn, out);
}